// Round 3
// baseline (6907.687 us; speedup 1.0000x reference)
//
#include <hip/hip_runtime.h>
#include <hip/hip_bf16.h>
#include <math.h>

// Problem constants
#define B_    2
#define T_    1024
#define D_    4096
#define H_    32
#define KVH_  8
#define HD_   128
#define GROUP_ 4

static constexpr float SCORE_SCALE = 0.08838834764831845f; // 1/sqrt(128)

__device__ inline float toF(const __hip_bfloat16 v) { return __bfloat162float(v); }
__device__ inline float toF(const float v)          { return v; }

__device__ inline void storeC(float* p, float v)          { *p = v; }
__device__ inline void storeC(__hip_bfloat16* p, float v) { *p = __float2bfloat16(v); }

// ---------------------------------------------------------------------------
// Tiled GEMM: C[M,N] = A[M,K] @ B[K,N], row-major, fp32 accumulate.
// 128x128 block tile, BK=16, 256 threads, 8x8 micro-tile per thread.
// M,N,K assumed multiples of 128/128/16 (true for all calls here).
// ---------------------------------------------------------------------------
template <typename TA, typename TB, typename TC>
__global__ __launch_bounds__(256) void gemm_tiled(const TA* __restrict__ A,
                                                  const TB* __restrict__ B,
                                                  TC* __restrict__ C,
                                                  int M, int N, int K) {
    __shared__ float As[128][17];   // [row][k]
    __shared__ float Bs[16][129];   // [k][col]

    const int tid = threadIdx.x;
    const int tx  = tid & 15;       // 0..15 -> col group
    const int ty  = tid >> 4;       // 0..15 -> row group
    const int bm  = blockIdx.y * 128;
    const int bn  = blockIdx.x * 128;

    float acc[8][8];
#pragma unroll
    for (int i = 0; i < 8; ++i)
#pragma unroll
        for (int j = 0; j < 8; ++j) acc[i][j] = 0.f;

    for (int k0 = 0; k0 < K; k0 += 16) {
        // stage A tile: 128x16 = 2048 elems, 8 per thread
#pragma unroll
        for (int e = 0; e < 8; ++e) {
            int idx = tid + e * 256;
            int r = idx >> 4, c = idx & 15;
            As[r][c] = toF(A[(size_t)(bm + r) * K + k0 + c]);
        }
        // stage B tile: 16x128 = 2048 elems, 8 per thread
#pragma unroll
        for (int e = 0; e < 8; ++e) {
            int idx = tid + e * 256;
            int r = idx >> 7, c = idx & 127;
            Bs[r][c] = toF(B[(size_t)(k0 + r) * N + bn + c]);
        }
        __syncthreads();

#pragma unroll
        for (int kk = 0; kk < 16; ++kk) {
            float ra[8], rb[8];
#pragma unroll
            for (int i = 0; i < 8; ++i) ra[i] = As[ty * 8 + i][kk];
#pragma unroll
            for (int j = 0; j < 8; ++j) rb[j] = Bs[kk][tx * 8 + j];
#pragma unroll
            for (int i = 0; i < 8; ++i)
#pragma unroll
                for (int j = 0; j < 8; ++j) acc[i][j] += ra[i] * rb[j];
        }
        __syncthreads();
    }

#pragma unroll
    for (int i = 0; i < 8; ++i) {
        size_t row = (size_t)(bm + ty * 8 + i);
#pragma unroll
        for (int j = 0; j < 8; ++j) {
            storeC(&C[row * N + bn + tx * 8 + j], acc[i][j]);
        }
    }
}

// ---------------------------------------------------------------------------
// RoPE in-place on Q (B*T x H*HD, fp32) and K (B*T x KVH*HD, bf16).
// Interleaved-pair rotation; cos/sin cache index = dim % (HD/2) (concat cache):
//   out[2i]   = x[2i]  *cos(a(2i))   - x[2i+1]*sin(a(2i))
//   out[2i+1] = x[2i+1]*cos(a(2i+1)) + x[2i]  *sin(a(2i+1))
//   a(d) = pos * ROPE_BASE^(-2*(d%64)/128)
// One wave per (token, head) row. 40 head-rows per token (32 Q + 8 K).
// ---------------------------------------------------------------------------
template <typename TQ, typename TK>
__global__ __launch_bounds__(256) void rope_kernel(TQ* __restrict__ Q,
                                                   TK* __restrict__ Kt,
                                                   const int* __restrict__ start_pos) {
    int w    = blockIdx.x * 4 + (threadIdx.x >> 6);
    int lane = threadIdx.x & 63;
    int hh = w % (H_ + KVH_);
    int n  = w / (H_ + KVH_);          // 0..B*T-1
    int t  = n % T_;
    int pos = *start_pos + t;

    int e0 = 2 * lane, e1 = 2 * lane + 1;
    int j0 = e0 & 63,  j1 = e1 & 63;
    const double LN_BASE = 9.210340371976184; // ln(10000)
    double a0 = (double)pos * exp(-((double)(2 * j0) / 128.0) * LN_BASE);
    double a1 = (double)pos * exp(-((double)(2 * j1) / 128.0) * LN_BASE);
    float c0 = (float)cos(a0), s0 = (float)sin(a0);
    float c1 = (float)cos(a1), s1 = (float)sin(a1);

    if (hh < H_) {
        TQ* base = Q + (size_t)n * (H_ * HD_) + hh * HD_;
        float x0 = toF(base[e0]), x1 = toF(base[e1]);
        storeC(&base[e0], x0 * c0 - x1 * s0);
        storeC(&base[e1], x1 * c1 + x0 * s1);
    } else {
        TK* base = Kt + (size_t)n * (KVH_ * HD_) + (hh - H_) * HD_;
        float x0 = toF(base[e0]), x1 = toF(base[e1]);
        storeC(&base[e0], x0 * c0 - x1 * s0);
        storeC(&base[e1], x1 * c1 + x0 * s1);
    }
}

// ---------------------------------------------------------------------------
// Causal GQA attention, online softmax. One wave per (b, h, q) row.
// Q: (B*T, H*HD) fp32, K/V: (B*T, KVH*HD) bf16, AO: (B*T, H*HD) bf16.
// Lane holds dims {lane, lane+64} of the 128-dim head. No +/-inf arithmetic.
// ---------------------------------------------------------------------------
__global__ __launch_bounds__(256) void attn_kernel(const float* __restrict__ Q,
                                                   const __hip_bfloat16* __restrict__ K,
                                                   const __hip_bfloat16* __restrict__ V,
                                                   __hip_bfloat16* __restrict__ AO) {
    int w    = blockIdx.x * 4 + (threadIdx.x >> 6);
    int lane = threadIdx.x & 63;
    int q = w % T_;
    int h = (w / T_) % H_;
    int b = w / (T_ * H_);
    int kvh = h / GROUP_;

    const float* qp = Q + (size_t)(b * T_ + q) * (H_ * HD_) + h * HD_;
    float q0 = qp[lane]      * SCORE_SCALE;
    float q1 = qp[lane + 64] * SCORE_SCALE;

    const __hip_bfloat16* Kb = K + (size_t)b * T_ * (KVH_ * HD_) + kvh * HD_;
    const __hip_bfloat16* Vb = V + (size_t)b * T_ * (KVH_ * HD_) + kvh * HD_;

    float m = -1e30f, l = 0.f, o0 = 0.f, o1 = 0.f;

    for (int t = 0; t <= q; ++t) {
        const __hip_bfloat16* kp = Kb + (size_t)t * (KVH_ * HD_);
        float s = q0 * toF(kp[lane]) + q1 * toF(kp[lane + 64]);
        // butterfly reduce across 64 lanes
#pragma unroll
        for (int off = 32; off >= 1; off >>= 1)
            s += __shfl_xor(s, off, 64);

        float nm = fmaxf(m, s);
        float sc = __expf(m - nm);   // ~0 on first iter (m = -1e30)
        float ex = __expf(s - nm);
        l = l * sc + ex;
        const __hip_bfloat16* vp = Vb + (size_t)t * (KVH_ * HD_);
        o0 = o0 * sc + ex * toF(vp[lane]);
        o1 = o1 * sc + ex * toF(vp[lane + 64]);
        m = nm;
    }

    float inv_l = 1.f / l;
    __hip_bfloat16* op = AO + (size_t)(b * T_ + q) * (H_ * HD_) + h * HD_;
    op[lane]      = __float2bfloat16(o0 * inv_l);
    op[lane + 64] = __float2bfloat16(o1 * inv_l);
}

// ---------------------------------------------------------------------------
extern "C" void kernel_launch(void* const* d_in, const int* in_sizes, int n_in,
                              void* d_out, int out_size, void* d_ws, size_t ws_size,
                              hipStream_t stream) {
    // Reference dtypes: all tensors float32; start_pos int32.
    const float* x  = (const float*)d_in[0];
    const float* wq = (const float*)d_in[1];
    const float* wk = (const float*)d_in[2];
    const float* wv = (const float*)d_in[3];
    const float* wo = (const float*)d_in[4];
    const int* start_pos = (const int*)d_in[5];
    float* out = (float*)d_out;

    // Scratch plan:
    //   Q fp32 lives in d_out itself (8M floats = exactly out_size; dead
    //   before the final GEMM overwrites it).
    //   d_ws (24 MiB): K bf16 (2M) | V bf16 (2M) | AO bf16 (8M)
    float* Qf           = out;
    __hip_bfloat16* Kb  = (__hip_bfloat16*)d_ws;
    __hip_bfloat16* Vb  = Kb + (size_t)B_ * T_ * KVH_ * HD_;   // +2097152
    __hip_bfloat16* AOb = Vb + (size_t)B_ * T_ * KVH_ * HD_;   // +2097152

    dim3 blk(256);
    const int M = B_ * T_;        // 2048
    const int NQ = H_ * HD_;      // 4096
    const int NKV = KVH_ * HD_;   // 1024

    // projections
    gemm_tiled<<<dim3(NQ / 128, M / 128), blk, 0, stream>>>(x, wq, Qf, M, NQ, D_);
    gemm_tiled<<<dim3(NKV / 128, M / 128), blk, 0, stream>>>(x, wk, Kb, M, NKV, D_);
    gemm_tiled<<<dim3(NKV / 128, M / 128), blk, 0, stream>>>(x, wv, Vb, M, NKV, D_);

    // RoPE on Q and K: B*T tokens * (H + KVH) head-rows, 1 wave each
    rope_kernel<<<(M * (H_ + KVH_)) / 4, blk, 0, stream>>>(Qf, Kb, start_pos);

    // attention: B*H*T waves, 4 per block
    attn_kernel<<<(B_ * H_ * T_) / 4, blk, 0, stream>>>(Qf, Kb, Vb, AOb);

    // output projection -> fp32 out (overwrites Q region, which is now dead)
    gemm_tiled<<<dim3(D_ / 128, M / 128), blk, 0, stream>>>(AOb, wo, out, M, D_, NQ);
}

// Round 5
// 4999.685 us; speedup vs baseline: 1.3816x; 1.3816x over previous
//
#include <hip/hip_runtime.h>
#include <hip/hip_bf16.h>
#include <math.h>

// Problem constants
#define B_    2
#define T_    1024
#define D_    4096
#define H_    32
#define KVH_  8
#define HD_   128
#define GROUP_ 4

static constexpr float SCORE_SCALE = 0.08838834764831845f; // 1/sqrt(128)

typedef __bf16 bf16x8 __attribute__((ext_vector_type(8)));
typedef float  f32x4  __attribute__((ext_vector_type(4)));

__device__ inline float toF(const __hip_bfloat16 v) { return __bfloat162float(v); }
__device__ inline float toF(const float v)          { return v; }

__device__ inline void storeC(float* p, float v)          { *p = v; }
__device__ inline void storeC(__hip_bfloat16* p, float v) { *p = __float2bfloat16(v); }

// fp32 -> bf16 bit pattern, round-to-nearest-even (finite inputs)
__device__ inline unsigned short f2bf(float f) {
    union { float f; unsigned u; } v; v.f = f;
    unsigned r = v.u + 0x7FFFu + ((v.u >> 16) & 1u);
    return (unsigned short)(r >> 16);
}

// ---------------------------------------------------------------------------
// MFMA GEMM: C[M,N] = A[M,K] @ B[K,N], row-major inputs (any of fp32/bf16),
// bf16 MFMA with fp32 accumulate. BM=BN=128, BK=32, 256 threads = 4 waves,
// each wave computes a 64x64 sub-tile as 4x4 mfma_f32_16x16x32_bf16.
// LDS: As[m][k] and Bs[n][k] (B transposed at staging), stride 40 ushorts
// (80 B: 16B-aligned for ds_read_b128, non-pow2 to spread banks).
// If DUAL: blockIdx.z selects (B0,C0) or (B1,C1) — used to fuse K/V proj.
// ---------------------------------------------------------------------------
#define LSTR 40

template <typename TA, typename TB, typename TC, bool DUAL>
__global__ __launch_bounds__(256) void gemm_mfma(const TA* __restrict__ A,
                                                 const TB* __restrict__ B0,
                                                 TC* __restrict__ C0,
                                                 const TB* __restrict__ B1,
                                                 TC* __restrict__ C1,
                                                 int M, int N, int K) {
    const TB* __restrict__ B = (DUAL && blockIdx.z) ? B1 : B0;
    TC* __restrict__ C       = (DUAL && blockIdx.z) ? C1 : C0;

    __shared__ unsigned short As[128 * LSTR];
    __shared__ unsigned short Bs[128 * LSTR];

    const int tid   = threadIdx.x;
    const int lane  = tid & 63;
    const int wv    = tid >> 6;       // 0..3
    const int waveM = wv >> 1;        // 0..1
    const int waveN = wv & 1;         // 0..1
    const int lm    = lane & 15;
    const int quad  = lane >> 4;      // 0..3
    const int bm    = blockIdx.y * 128;
    const int bn    = blockIdx.x * 128;

    f32x4 acc[4][4];
#pragma unroll
    for (int i = 0; i < 4; ++i)
#pragma unroll
        for (int j = 0; j < 4; ++j) acc[i][j] = (f32x4){0.f, 0.f, 0.f, 0.f};

    for (int k0 = 0; k0 < K; k0 += 32) {
        // --- stage A tile: 128 rows x 32 k, pairs along k --------------------
#pragma unroll
        for (int e = 0; e < 8; ++e) {
            int p  = tid + e * 256;          // 0..2047 (pair index)
            int r  = p >> 4;                 // 0..127
            int c2 = (p & 15) * 2;           // 0,2,..,30
            const TA* ap = A + (size_t)(bm + r) * K + k0 + c2;
            ushort2 t;
            t.x = f2bf(toF(ap[0]));
            t.y = f2bf(toF(ap[1]));
            *(ushort2*)&As[r * LSTR + c2] = t;
        }
        // --- stage B tile transposed: Bs[n][k], pairs along k ----------------
#pragma unroll
        for (int e = 0; e < 8; ++e) {
            int p  = tid + e * 256;          // 0..2047
            int n  = p & 127;
            int k2 = (p >> 7) * 2;           // 0,2,..,30
            const TB* bp = B + (size_t)(k0 + k2) * N + bn + n;
            ushort2 t;
            t.x = f2bf(toF(bp[0]));
            t.y = f2bf(toF(bp[N]));
            *(ushort2*)&Bs[n * LSTR + k2] = t;
        }
        __syncthreads();

        // --- fragments + 16 MFMAs -------------------------------------------
        bf16x8 af[4], bfr[4];
#pragma unroll
        for (int i = 0; i < 4; ++i)
            af[i] = *(const bf16x8*)&As[(waveM * 64 + i * 16 + lm) * LSTR + quad * 8];
#pragma unroll
        for (int j = 0; j < 4; ++j)
            bfr[j] = *(const bf16x8*)&Bs[(waveN * 64 + j * 16 + lm) * LSTR + quad * 8];
#pragma unroll
        for (int i = 0; i < 4; ++i)
#pragma unroll
            for (int j = 0; j < 4; ++j)
                acc[i][j] = __builtin_amdgcn_mfma_f32_16x16x32_bf16(af[i], bfr[j], acc[i][j], 0, 0, 0);
        __syncthreads();
    }

    // --- epilogue: C/D layout col=lane&15, row=quad*4+reg --------------------
#pragma unroll
    for (int i = 0; i < 4; ++i) {
        int row0 = bm + waveM * 64 + i * 16 + quad * 4;
#pragma unroll
        for (int j = 0; j < 4; ++j) {
            int col = bn + waveN * 64 + j * 16 + lm;
#pragma unroll
            for (int rr = 0; rr < 4; ++rr)
                storeC(&C[(size_t)(row0 + rr) * N + col], acc[i][j][rr]);
        }
    }
}

// ---------------------------------------------------------------------------
// RoPE in-place on Q (B*T x H*HD, fp32) and K (B*T x KVH*HD, bf16).
// Interleaved-pair rotation; cos/sin cache index = dim % (HD/2) (concat cache)
// ---------------------------------------------------------------------------
template <typename TQ, typename TK>
__global__ __launch_bounds__(256) void rope_kernel(TQ* __restrict__ Q,
                                                   TK* __restrict__ Kt,
                                                   const int* __restrict__ start_pos) {
    int w    = blockIdx.x * 4 + (threadIdx.x >> 6);
    int lane = threadIdx.x & 63;
    int hh = w % (H_ + KVH_);
    int n  = w / (H_ + KVH_);          // 0..B*T-1
    int t  = n % T_;
    int pos = *start_pos + t;

    int e0 = 2 * lane, e1 = 2 * lane + 1;
    int j0 = e0 & 63,  j1 = e1 & 63;
    const double LN_BASE = 9.210340371976184; // ln(10000)
    double a0 = (double)pos * exp(-((double)(2 * j0) / 128.0) * LN_BASE);
    double a1 = (double)pos * exp(-((double)(2 * j1) / 128.0) * LN_BASE);
    float c0 = (float)cos(a0), s0 = (float)sin(a0);
    float c1 = (float)cos(a1), s1 = (float)sin(a1);

    if (hh < H_) {
        TQ* base = Q + (size_t)n * (H_ * HD_) + hh * HD_;
        float x0 = toF(base[e0]), x1 = toF(base[e1]);
        storeC(&base[e0], x0 * c0 - x1 * s0);
        storeC(&base[e1], x1 * c1 + x0 * s1);
    } else {
        TK* base = Kt + (size_t)n * (KVH_ * HD_) + (hh - H_) * HD_;
        float x0 = toF(base[e0]), x1 = toF(base[e1]);
        storeC(&base[e0], x0 * c0 - x1 * s0);
        storeC(&base[e1], x1 * c1 + x0 * s1);
    }
}

// ---------------------------------------------------------------------------
// Causal GQA attention, online softmax. One wave per (b, h, q) row.
// Q: (B*T, H*HD) fp32, K/V: (B*T, KVH*HD) bf16, AO: (B*T, H*HD) bf16.
// ---------------------------------------------------------------------------
__global__ __launch_bounds__(256) void attn_kernel(const float* __restrict__ Q,
                                                   const __hip_bfloat16* __restrict__ K,
                                                   const __hip_bfloat16* __restrict__ V,
                                                   __hip_bfloat16* __restrict__ AO) {
    int w    = blockIdx.x * 4 + (threadIdx.x >> 6);
    int lane = threadIdx.x & 63;
    int q = w % T_;
    int h = (w / T_) % H_;
    int b = w / (T_ * H_);
    int kvh = h / GROUP_;

    const float* qp = Q + (size_t)(b * T_ + q) * (H_ * HD_) + h * HD_;
    float q0 = qp[lane]      * SCORE_SCALE;
    float q1 = qp[lane + 64] * SCORE_SCALE;

    const __hip_bfloat16* Kb = K + (size_t)b * T_ * (KVH_ * HD_) + kvh * HD_;
    const __hip_bfloat16* Vb = V + (size_t)b * T_ * (KVH_ * HD_) + kvh * HD_;

    float m = -1e30f, l = 0.f, o0 = 0.f, o1 = 0.f;

    for (int t = 0; t <= q; ++t) {
        const __hip_bfloat16* kp = Kb + (size_t)t * (KVH_ * HD_);
        float s = q0 * toF(kp[lane]) + q1 * toF(kp[lane + 64]);
#pragma unroll
        for (int off = 32; off >= 1; off >>= 1)
            s += __shfl_xor(s, off, 64);

        float nm = fmaxf(m, s);
        float sc = __expf(m - nm);
        float ex = __expf(s - nm);
        l = l * sc + ex;
        const __hip_bfloat16* vp = Vb + (size_t)t * (KVH_ * HD_);
        o0 = o0 * sc + ex * toF(vp[lane]);
        o1 = o1 * sc + ex * toF(vp[lane + 64]);
        m = nm;
    }

    float inv_l = 1.f / l;
    __hip_bfloat16* op = AO + (size_t)(b * T_ + q) * (H_ * HD_) + h * HD_;
    op[lane]      = __float2bfloat16(o0 * inv_l);
    op[lane + 64] = __float2bfloat16(o1 * inv_l);
}

// ---------------------------------------------------------------------------
extern "C" void kernel_launch(void* const* d_in, const int* in_sizes, int n_in,
                              void* d_out, int out_size, void* d_ws, size_t ws_size,
                              hipStream_t stream) {
    // Reference dtypes: all tensors float32; start_pos int32.
    const float* x  = (const float*)d_in[0];
    const float* wq = (const float*)d_in[1];
    const float* wk = (const float*)d_in[2];
    const float* wv = (const float*)d_in[3];
    const float* wo = (const float*)d_in[4];
    const int* start_pos = (const int*)d_in[5];
    float* out = (float*)d_out;

    // Scratch: Q fp32 lives in d_out (8M floats, dead before final GEMM).
    // d_ws (24 MiB): K bf16 (2M) | V bf16 (2M) | AO bf16 (8M)
    float* Qf           = out;
    __hip_bfloat16* Kb  = (__hip_bfloat16*)d_ws;
    __hip_bfloat16* Vb  = Kb + (size_t)B_ * T_ * KVH_ * HD_;
    __hip_bfloat16* AOb = Vb + (size_t)B_ * T_ * KVH_ * HD_;

    dim3 blk(256);
    const int M = B_ * T_;        // 2048
    const int NQ = H_ * HD_;      // 4096
    const int NKV = KVH_ * HD_;   // 1024

    // Q projection: 2048x4096x4096
    gemm_mfma<float, float, float, false>
        <<<dim3(NQ / 128, M / 128, 1), blk, 0, stream>>>(x, wq, Qf, nullptr, nullptr, M, NQ, D_);
    // K and V projections fused via blockIdx.z: 2048x1024x4096 each
    gemm_mfma<float, float, __hip_bfloat16, true>
        <<<dim3(NKV / 128, M / 128, 2), blk, 0, stream>>>(x, wk, Kb, wv, Vb, M, NKV, D_);

    // RoPE on Q and K
    rope_kernel<<<(M * (H_ + KVH_)) / 4, blk, 0, stream>>>(Qf, Kb, start_pos);

    // attention: B*H*T waves, 4 per block
    attn_kernel<<<(B_ * H_ * T_) / 4, blk, 0, stream>>>(Qf, Kb, Vb, AOb);

    // output projection: 2048x4096x4096 -> fp32 out (Q region now dead)
    gemm_mfma<__hip_bfloat16, float, float, false>
        <<<dim3(D_ / 128, M / 128, 1), blk, 0, stream>>>(AOb, wo, out, nullptr, nullptr, M, D_, NQ);
}

// Round 6
// 2402.747 us; speedup vs baseline: 2.8749x; 2.0808x over previous
//
#include <hip/hip_runtime.h>
#include <hip/hip_bf16.h>
#include <math.h>

// Problem constants
#define B_    2
#define T_    1024
#define D_    4096
#define H_    32
#define KVH_  8
#define HD_   128
#define GROUP_ 4

static constexpr float SCORE_SCALE = 0.08838834764831845f; // 1/sqrt(128)

typedef __bf16 bf16x8 __attribute__((ext_vector_type(8)));
typedef float  f32x4  __attribute__((ext_vector_type(4)));

__device__ inline float toF(const __hip_bfloat16 v) { return __bfloat162float(v); }
__device__ inline float toF(const float v)          { return v; }

__device__ inline void storeC(float* p, float v)          { *p = v; }
__device__ inline void storeC(__hip_bfloat16* p, float v) { *p = __float2bfloat16(v); }

// fp32 -> bf16 bit pattern, round-to-nearest-even (finite inputs)
__device__ inline unsigned short f2bf(float f) {
    union { float f; unsigned u; } v; v.f = f;
    unsigned r = v.u + 0x7FFFu + ((v.u >> 16) & 1u);
    return (unsigned short)(r >> 16);
}

// ---------------------------------------------------------------------------
// MFMA GEMM: C[M,N] = A[M,K] @ B[K,N], row-major, bf16 MFMA fp32 accumulate.
// BM=BN=128, BK=32, 4 waves x (64x64 as 4x4 mfma_f32_16x16x32_bf16).
// DUAL: blockIdx.z picks (B0,C0)/(B1,C1). TRC1: the z=1 output is stored
// transposed (C1[col*M + row]) — used to produce V^T for flash attention.
// ---------------------------------------------------------------------------
#define LSTR 40

template <typename TA, typename TB, typename TC, bool DUAL, bool TRC1>
__global__ __launch_bounds__(256) void gemm_mfma(const TA* __restrict__ A,
                                                 const TB* __restrict__ B0,
                                                 TC* __restrict__ C0,
                                                 const TB* __restrict__ B1,
                                                 TC* __restrict__ C1,
                                                 int M, int N, int K) {
    const TB* __restrict__ B = (DUAL && blockIdx.z) ? B1 : B0;
    TC* __restrict__ C       = (DUAL && blockIdx.z) ? C1 : C0;

    __shared__ unsigned short As[128 * LSTR];
    __shared__ unsigned short Bs[128 * LSTR];

    const int tid   = threadIdx.x;
    const int lane  = tid & 63;
    const int wv    = tid >> 6;
    const int waveM = wv >> 1;
    const int waveN = wv & 1;
    const int lm    = lane & 15;
    const int quad  = lane >> 4;
    const int bm    = blockIdx.y * 128;
    const int bn    = blockIdx.x * 128;

    f32x4 acc[4][4];
#pragma unroll
    for (int i = 0; i < 4; ++i)
#pragma unroll
        for (int j = 0; j < 4; ++j) acc[i][j] = (f32x4){0.f, 0.f, 0.f, 0.f};

    for (int k0 = 0; k0 < K; k0 += 32) {
#pragma unroll
        for (int e = 0; e < 8; ++e) {
            int p  = tid + e * 256;
            int r  = p >> 4, c2 = (p & 15) * 2;
            const TA* ap = A + (size_t)(bm + r) * K + k0 + c2;
            ushort2 t;
            t.x = f2bf(toF(ap[0]));
            t.y = f2bf(toF(ap[1]));
            *(ushort2*)&As[r * LSTR + c2] = t;
        }
#pragma unroll
        for (int e = 0; e < 8; ++e) {
            int p  = tid + e * 256;
            int n  = p & 127, k2 = (p >> 7) * 2;
            const TB* bp = B + (size_t)(k0 + k2) * N + bn + n;
            ushort2 t;
            t.x = f2bf(toF(bp[0]));
            t.y = f2bf(toF(bp[N]));
            *(ushort2*)&Bs[n * LSTR + k2] = t;
        }
        __syncthreads();

        bf16x8 af[4], bfr[4];
#pragma unroll
        for (int i = 0; i < 4; ++i)
            af[i] = *(const bf16x8*)&As[(waveM * 64 + i * 16 + lm) * LSTR + quad * 8];
#pragma unroll
        for (int j = 0; j < 4; ++j)
            bfr[j] = *(const bf16x8*)&Bs[(waveN * 64 + j * 16 + lm) * LSTR + quad * 8];
#pragma unroll
        for (int i = 0; i < 4; ++i)
#pragma unroll
            for (int j = 0; j < 4; ++j)
                acc[i][j] = __builtin_amdgcn_mfma_f32_16x16x32_bf16(af[i], bfr[j], acc[i][j], 0, 0, 0);
        __syncthreads();
    }

    // C/D layout: col = lane&15, row = quad*4 + reg  [m89-verified]
    if (TRC1 && DUAL && blockIdx.z) {
#pragma unroll
        for (int i = 0; i < 4; ++i) {
            int row0 = bm + waveM * 64 + i * 16 + quad * 4;
#pragma unroll
            for (int j = 0; j < 4; ++j) {
                int col = bn + waveN * 64 + j * 16 + lm;
#pragma unroll
                for (int rr = 0; rr < 4; ++rr)
                    storeC(&C[(size_t)col * M + row0 + rr], acc[i][j][rr]);
            }
        }
    } else {
#pragma unroll
        for (int i = 0; i < 4; ++i) {
            int row0 = bm + waveM * 64 + i * 16 + quad * 4;
#pragma unroll
            for (int j = 0; j < 4; ++j) {
                int col = bn + waveN * 64 + j * 16 + lm;
#pragma unroll
                for (int rr = 0; rr < 4; ++rr)
                    storeC(&C[(size_t)(row0 + rr) * N + col], acc[i][j][rr]);
            }
        }
    }
}

// ---------------------------------------------------------------------------
// RoPE in-place on Q (fp32, [token][H*HD]) and K (bf16, [token][KVH*HD]).
// ---------------------------------------------------------------------------
template <typename TQ, typename TK>
__global__ __launch_bounds__(256) void rope_kernel(TQ* __restrict__ Q,
                                                   TK* __restrict__ Kt,
                                                   const int* __restrict__ start_pos) {
    int w    = blockIdx.x * 4 + (threadIdx.x >> 6);
    int lane = threadIdx.x & 63;
    int hh = w % (H_ + KVH_);
    int n  = w / (H_ + KVH_);
    int t  = n % T_;
    int pos = *start_pos + t;

    int e0 = 2 * lane, e1 = 2 * lane + 1;
    int j0 = e0 & 63,  j1 = e1 & 63;
    const double LN_BASE = 9.210340371976184; // ln(10000)
    double a0 = (double)pos * exp(-((double)(2 * j0) / 128.0) * LN_BASE);
    double a1 = (double)pos * exp(-((double)(2 * j1) / 128.0) * LN_BASE);
    float c0 = (float)cos(a0), s0 = (float)sin(a0);
    float c1 = (float)cos(a1), s1 = (float)sin(a1);

    if (hh < H_) {
        TQ* base = Q + (size_t)n * (H_ * HD_) + hh * HD_;
        float x0 = toF(base[e0]), x1 = toF(base[e1]);
        storeC(&base[e0], x0 * c0 - x1 * s0);
        storeC(&base[e1], x1 * c1 + x0 * s1);
    } else {
        TK* base = Kt + (size_t)n * (KVH_ * HD_) + (hh - H_) * HD_;
        float x0 = toF(base[e0]), x1 = toF(base[e1]);
        storeC(&base[e0], x0 * c0 - x1 * s0);
        storeC(&base[e1], x1 * c1 + x0 * s1);
    }
}

// ---------------------------------------------------------------------------
// Flash attention (causal, GQA). Workgroup = (128 q-rows, head h, batch b);
// 4 waves, each owns 32 q rows (2 m-tiles of 16). K-tiles of 64 positions.
// Q fp32 [token][H*HD]; K bf16 [token][KVH*HD]; Vt bf16 [KVH*HD][B*T] (V^T);
// AO bf16 [token][H*HD].
// S = QK^T via mfma_16x16x32 (C/D: col=t-lane, row=quad*4+reg); online
// softmax per row with per-quad shfl_xor reduce; P -> LDS (bf16) round-trip
// to A-layout [m120 pattern]; O += P V via mfma with V^T frags from LDS.
// ---------------------------------------------------------------------------
#define KSTR 136   // Ks row stride (ushorts): 128 + 8 -> 2-way banks, 16B-aligned
#define VSTR 72    // Vs row stride: 64 + 8
#define PSTR 72    // Ps row stride

__global__ __launch_bounds__(256, 2) void flash_attn(
        const float* __restrict__ Q,
        const __hip_bfloat16* __restrict__ K,
        const __hip_bfloat16* __restrict__ Vt,
        __hip_bfloat16* __restrict__ AO) {
    __shared__ unsigned short Ks[64 * KSTR];       // 17408 B
    __shared__ unsigned short Vs[128 * VSTR];      // 18432 B
    __shared__ unsigned short Ps[4][32 * PSTR];    // 18432 B  (per-wave private)

    const int tid  = threadIdx.x;
    const int lane = tid & 63;
    const int w    = tid >> 6;
    const int quad = lane >> 4;
    const int lm   = lane & 15;

    const int qb  = blockIdx.x * 128;
    const int h   = blockIdx.y;
    const int b   = blockIdx.z;
    const int kvh = h >> 2;           // GROUP_=4 query heads per KV head

    const int qw = qb + w * 32;       // wave's first q row

    // Q fragments in registers (A-layout: m=lm, k=quad*8+j), pre-scaled.
    bf16x8 qf[2][4];
#pragma unroll
    for (int mt = 0; mt < 2; ++mt) {
        const float* qrow = Q + (size_t)(b * T_ + qw + mt * 16 + lm) * (H_ * HD_) + h * HD_;
#pragma unroll
        for (int ks = 0; ks < 4; ++ks) {
            const float* p4 = qrow + ks * 32 + quad * 8;
            float4 f0 = *(const float4*)(p4);
            float4 f1 = *(const float4*)(p4 + 4);
            union { bf16x8 v; unsigned short u[8]; } t;
            t.u[0] = f2bf(f0.x * SCORE_SCALE); t.u[1] = f2bf(f0.y * SCORE_SCALE);
            t.u[2] = f2bf(f0.z * SCORE_SCALE); t.u[3] = f2bf(f0.w * SCORE_SCALE);
            t.u[4] = f2bf(f1.x * SCORE_SCALE); t.u[5] = f2bf(f1.y * SCORE_SCALE);
            t.u[6] = f2bf(f1.z * SCORE_SCALE); t.u[7] = f2bf(f1.w * SCORE_SCALE);
            qf[mt][ks] = t.v;
        }
    }

    float mI[2][4], lI[2][4];
    f32x4 o[2][8];
#pragma unroll
    for (int mt = 0; mt < 2; ++mt) {
#pragma unroll
        for (int rr = 0; rr < 4; ++rr) { mI[mt][rr] = -1e30f; lI[mt][rr] = 0.f; }
#pragma unroll
        for (int dc = 0; dc < 8; ++dc) o[mt][dc] = (f32x4){0.f, 0.f, 0.f, 0.f};
    }

    const int nkt  = (qb + 128) / 64;   // k-tiles covering t <= q for this block
    const int qmax = qw + 31;

    for (int kt = 0; kt < nkt; ++kt) {
        const int t0 = kt * 64;
        // --- cooperative staging: K tile [64][128], V^T tile [128][64] -------
#pragma unroll
        for (int e = 0; e < 4; ++e) {
            int p = tid + e * 256;
            int tt = p >> 4, d0 = (p & 15) * 8;
            int4 v = *(const int4*)(K + (size_t)(b * T_ + t0 + tt) * (KVH_ * HD_) + kvh * HD_ + d0);
            *(int4*)&Ks[tt * KSTR + d0] = v;
        }
#pragma unroll
        for (int e = 0; e < 4; ++e) {
            int p = tid + e * 256;
            int d = p >> 3, tm = (p & 7) * 8;
            int4 v = *(const int4*)(Vt + (size_t)(kvh * HD_ + d) * (B_ * T_) + b * T_ + t0 + tm);
            *(int4*)&Vs[d * VSTR + tm] = v;
        }
        __syncthreads();

        if (t0 <= qmax) {
            // --- S = Q K^T ---------------------------------------------------
            f32x4 s[2][4];
#pragma unroll
            for (int mt = 0; mt < 2; ++mt)
#pragma unroll
                for (int tc = 0; tc < 4; ++tc) s[mt][tc] = (f32x4){0.f, 0.f, 0.f, 0.f};
#pragma unroll
            for (int ks = 0; ks < 4; ++ks) {
                bf16x8 kf[4];
#pragma unroll
                for (int tc = 0; tc < 4; ++tc)
                    kf[tc] = *(const bf16x8*)&Ks[(tc * 16 + lm) * KSTR + ks * 32 + quad * 8];
#pragma unroll
                for (int mt = 0; mt < 2; ++mt)
#pragma unroll
                    for (int tc = 0; tc < 4; ++tc)
                        s[mt][tc] = __builtin_amdgcn_mfma_f32_16x16x32_bf16(qf[mt][ks], kf[tc], s[mt][tc], 0, 0, 0);
            }

            // --- causal mask (edge tiles only) -------------------------------
            if (t0 + 63 > qw) {
#pragma unroll
                for (int mt = 0; mt < 2; ++mt) {
                    int qrow = qw + mt * 16 + quad * 4;
#pragma unroll
                    for (int tc = 0; tc < 4; ++tc) {
                        int tcol = t0 + tc * 16 + lm;
#pragma unroll
                        for (int rr = 0; rr < 4; ++rr)
                            if (tcol > qrow + rr) s[mt][tc][rr] = -1e30f;
                    }
                }
            }

            // --- online softmax ---------------------------------------------
#pragma unroll
            for (int mt = 0; mt < 2; ++mt) {
#pragma unroll
                for (int rr = 0; rr < 4; ++rr) {
                    float tmx = fmaxf(fmaxf(s[mt][0][rr], s[mt][1][rr]),
                                      fmaxf(s[mt][2][rr], s[mt][3][rr]));
#pragma unroll
                    for (int off = 8; off >= 1; off >>= 1)
                        tmx = fmaxf(tmx, __shfl_xor(tmx, off, 64));
                    float mn    = fmaxf(mI[mt][rr], tmx);
                    float alpha = __expf(mI[mt][rr] - mn);
                    mI[mt][rr]  = mn;
                    float rs = 0.f;
#pragma unroll
                    for (int tc = 0; tc < 4; ++tc) {
                        float p = __expf(s[mt][tc][rr] - mn);
                        s[mt][tc][rr] = p;
                        rs += p;
                    }
#pragma unroll
                    for (int off = 8; off >= 1; off >>= 1)
                        rs += __shfl_xor(rs, off, 64);
                    lI[mt][rr] = lI[mt][rr] * alpha + rs;
#pragma unroll
                    for (int dc = 0; dc < 8; ++dc)
                        o[mt][dc][rr] *= alpha;
                }
            }

            // --- P -> LDS (C/D layout -> A layout round trip) ----------------
#pragma unroll
            for (int mt = 0; mt < 2; ++mt)
#pragma unroll
                for (int tc = 0; tc < 4; ++tc)
#pragma unroll
                    for (int rr = 0; rr < 4; ++rr)
                        Ps[w][(mt * 16 + quad * 4 + rr) * PSTR + tc * 16 + lm] = f2bf(s[mt][tc][rr]);

            // --- O += P V ----------------------------------------------------
#pragma unroll
            for (int ss = 0; ss < 2; ++ss) {
                bf16x8 pf[2];
#pragma unroll
                for (int mt = 0; mt < 2; ++mt)
                    pf[mt] = *(const bf16x8*)&Ps[w][(mt * 16 + lm) * PSTR + ss * 32 + quad * 8];
#pragma unroll
                for (int dc = 0; dc < 8; ++dc) {
                    bf16x8 vf = *(const bf16x8*)&Vs[(dc * 16 + lm) * VSTR + ss * 32 + quad * 8];
#pragma unroll
                    for (int mt = 0; mt < 2; ++mt)
                        o[mt][dc] = __builtin_amdgcn_mfma_f32_16x16x32_bf16(pf[mt], vf, o[mt][dc], 0, 0, 0);
                }
            }
        }
        __syncthreads();
    }

    // --- epilogue: O /= l, store bf16 ---------------------------------------
#pragma unroll
    for (int mt = 0; mt < 2; ++mt) {
#pragma unroll
        for (int rr = 0; rr < 4; ++rr) {
            float inv = 1.f / lI[mt][rr];
            size_t row = (size_t)(b * T_ + qw + mt * 16 + quad * 4 + rr) * (H_ * HD_) + h * HD_;
#pragma unroll
            for (int dc = 0; dc < 8; ++dc)
                AO[row + dc * 16 + lm] = __float2bfloat16(o[mt][dc][rr] * inv);
        }
    }
}

// ---------------------------------------------------------------------------
extern "C" void kernel_launch(void* const* d_in, const int* in_sizes, int n_in,
                              void* d_out, int out_size, void* d_ws, size_t ws_size,
                              hipStream_t stream) {
    // Reference dtypes: all tensors float32; start_pos int32.
    const float* x  = (const float*)d_in[0];
    const float* wq = (const float*)d_in[1];
    const float* wk = (const float*)d_in[2];
    const float* wv = (const float*)d_in[3];
    const float* wo = (const float*)d_in[4];
    const int* start_pos = (const int*)d_in[5];
    float* out = (float*)d_out;

    // Q fp32 lives in d_out (8M floats; dead before final GEMM overwrites it).
    // d_ws (24 MiB): K bf16 [2048][1024] | Vt bf16 [1024][2048] (V^T) | AO bf16 [2048][4096]
    float* Qf           = out;
    __hip_bfloat16* Kb  = (__hip_bfloat16*)d_ws;
    __hip_bfloat16* Vtb = Kb + (size_t)B_ * T_ * KVH_ * HD_;
    __hip_bfloat16* AOb = Vtb + (size_t)B_ * T_ * KVH_ * HD_;

    dim3 blk(256);
    const int M = B_ * T_;        // 2048
    const int NQ = H_ * HD_;      // 4096
    const int NKV = KVH_ * HD_;   // 1024

    // Q projection: 2048x4096x4096
    gemm_mfma<float, float, float, false, false>
        <<<dim3(NQ / 128, M / 128, 1), blk, 0, stream>>>(x, wq, Qf, nullptr, nullptr, M, NQ, D_);
    // K and V projections fused; V output stored transposed (Vt[col][token])
    gemm_mfma<float, float, __hip_bfloat16, true, true>
        <<<dim3(NKV / 128, M / 128, 2), blk, 0, stream>>>(x, wk, Kb, wv, Vtb, M, NKV, D_);

    // RoPE on Q and K (V not roped)
    rope_kernel<<<(M * (H_ + KVH_)) / 4, blk, 0, stream>>>(Qf, Kb, start_pos);

    // Flash attention: grid (T/128, H, B)
    flash_attn<<<dim3(T_ / 128, H_, B_), blk, 0, stream>>>(Qf, Kb, Vtb, AOb);

    // output projection: 2048x4096x4096 -> fp32 out (Q region now dead)
    gemm_mfma<__hip_bfloat16, float, float, false, false>
        <<<dim3(D_ / 128, M / 128, 1), blk, 0, stream>>>(AOb, wo, out, nullptr, nullptr, M, D_, NQ);
}